// Round 3
// baseline (181.969 us; speedup 1.0000x reference)
//
#include <hip/hip_runtime.h>
#include <stdint.h>

#define BATCH 8
#define SEQ   2048
#define DIM   512

typedef __attribute__((ext_vector_type(8)))  short short8;    // 8 bf16 (4 VGPRs)
typedef __attribute__((ext_vector_type(16))) float floatx16;  // 32x32 C/D frag

static __device__ __forceinline__ unsigned short f32_bf16(float f) {
  unsigned u = __builtin_bit_cast(unsigned, f);
  u += 0x7FFFu + ((u >> 16) & 1u);          // round-to-nearest-even
  return (unsigned short)(u >> 16);
}
static __device__ __forceinline__ short8 ld_frag8(const unsigned short* p) {
  return __builtin_bit_cast(short8, *reinterpret_cast<const uint4*>(p));
}
static __device__ __forceinline__ void gld_lds16(const unsigned short* g, unsigned short* l) {
  __builtin_amdgcn_global_load_lds((const __attribute__((address_space(1))) unsigned int*)g,
                                   (__attribute__((address_space(3))) unsigned int*)l, 16, 0, 0);
}

// ---------------- prep: x -> xn (bf16 x-hat, row-major) and xt (bf16 x^T, [b][d][j]) --------
// grid 512 = 8 batches x 64 j-blocks of 32 rows ; 256 threads
__global__ __launch_bounds__(256) void prep_kernel(const float* __restrict__ x,
                                                   unsigned short* __restrict__ xn,
                                                   unsigned short* __restrict__ xt) {
  const int b  = blockIdx.x >> 6;
  const int jb = blockIdx.x & 63;
  const int t  = threadIdx.x;
  const int j  = t >> 3;   // 0..31 row in tile
  const int s  = t & 7;    // 0..7  d-octant (64 elems)

  __shared__ unsigned short xs[32 * 516];   // bf16(x) tile, stride 516
  __shared__ float rsum[32][8];
  __shared__ float scl[32];

  const long rowg = ((long)b * SEQ + (long)jb * 32 + j) * DIM;
  float vals[64];
  float acc = 0.f;
  const float4* xv = reinterpret_cast<const float4*>(x + rowg + s * 64);
#pragma unroll
  for (int k = 0; k < 16; ++k) {
    float4 v = xv[k];
    vals[4*k+0] = v.x; vals[4*k+1] = v.y; vals[4*k+2] = v.z; vals[4*k+3] = v.w;
    acc += v.x*v.x + v.y*v.y + v.z*v.z + v.w*v.w;
    ushort4 pk;
    pk.x = f32_bf16(v.x); pk.y = f32_bf16(v.y); pk.z = f32_bf16(v.z); pk.w = f32_bf16(v.w);
    *reinterpret_cast<ushort4*>(&xs[j * 516 + s * 64 + 4 * k]) = pk;
  }
  rsum[j][s] = acc;
  __syncthreads();
  if (t < 32) {
    float a = 0.f;
#pragma unroll
    for (int k = 0; k < 8; ++k) a += rsum[t][k];
    scl[t] = 1.f / (sqrtf(a) + 1e-12f);
  }
  __syncthreads();
  const float sc = scl[j];
  unsigned short* xnp = xn + rowg + s * 64;
#pragma unroll
  for (int k = 0; k < 16; ++k) {
    ushort4 pk;
    pk.x = f32_bf16(vals[4*k+0] * sc);
    pk.y = f32_bf16(vals[4*k+1] * sc);
    pk.z = f32_bf16(vals[4*k+2] * sc);
    pk.w = f32_bf16(vals[4*k+3] * sc);
    *reinterpret_cast<ushort4*>(xnp + 4 * k) = pk;
  }
  // xt: full transpose [b][d][j]; ds_read_b64 gathers, 16B coalesced writes
  unsigned short* xtb = xt + (long)b * DIM * SEQ;
#pragma unroll
  for (int u = t; u < 512; u += 256) {           // 512 units = 128 d-quads x 4 j-octants
    const int dq = u >> 2, jq = u & 3;
    ushort4 rv[8];
#pragma unroll
    for (int r = 0; r < 8; ++r)
      rv[r] = *reinterpret_cast<const ushort4*>(&xs[(jq * 8 + r) * 516 + dq * 4]);
#pragma unroll
    for (int dd = 0; dd < 4; ++dd) {
      const unsigned short* rp0 = (const unsigned short*)&rv[0];
      uint4 o;
      o.x = (unsigned)((const unsigned short*)&rv[0])[dd] | ((unsigned)((const unsigned short*)&rv[1])[dd] << 16);
      o.y = (unsigned)((const unsigned short*)&rv[2])[dd] | ((unsigned)((const unsigned short*)&rv[3])[dd] << 16);
      o.z = (unsigned)((const unsigned short*)&rv[4])[dd] | ((unsigned)((const unsigned short*)&rv[5])[dd] << 16);
      o.w = (unsigned)((const unsigned short*)&rv[6])[dd] | ((unsigned)((const unsigned short*)&rv[7])[dd] << 16);
      (void)rp0;
      *reinterpret_cast<uint4*>(xtb + (long)(dq * 4 + dd) * SEQ + jb * 32 + jq * 8) = o;
    }
  }
}

// ---------------- gemm1: P = bf16(exp(S^2-1)), S = xn.xn^T, SYMMETRIC upper-tri only ------
// grid 1088 = 8 batches x 136 upper-tri tile pairs ; also accumulates row sums l via atomics
__global__ __launch_bounds__(256, 3) void gemm1_kernel(const unsigned short* __restrict__ xn,
                                                       unsigned short* __restrict__ P,
                                                       float* __restrict__ lw) {
  const int b = blockIdx.x & 7;
  int rem = blockIdx.x >> 3;
  int ti = 0;
  while (rem >= 16 - ti) { rem -= 16 - ti; ++ti; }
  const int tj = ti + rem;
  const int i0 = ti * 128, j0 = tj * 128;

  const int tid  = threadIdx.x;
  const int w    = tid >> 6;
  const int lane = tid & 63;
  const int ln   = lane & 31;
  const int half = lane >> 5;

  __shared__ __align__(16) unsigned short smem[17408];   // staging 32KB ; epilogue sQ 128x136 (34816B)
  unsigned short* sA = smem;
  unsigned short* sB = smem + 8192;

  const unsigned short* xb = xn + (long)b * SEQ * DIM;
  const unsigned short* Ag = xb + (long)i0 * DIM;
  const unsigned short* Bg = xb + (long)j0 * DIM;

  floatx16 acc[2][2];
#pragma unroll
  for (int mt = 0; mt < 2; ++mt)
#pragma unroll
    for (int nt = 0; nt < 2; ++nt)
#pragma unroll
      for (int i = 0; i < 16; ++i) acc[mt][nt][i] = 0.f;

  const int r0 = (w >> 1) * 64;
  const int c0 = (w & 1) * 64;

  for (int kc = 0; kc < 8; ++kc) {
#pragma unroll
    for (int k = 0; k < 4; ++k) {
      int u = tid + k * 256;
      int row = u >> 3, c = u & 7;
      int gc = (c ^ (row & 7)) * 8;
      gld_lds16(Ag + (long)row * DIM + kc * 64 + gc, sA + u * 8);
      gld_lds16(Bg + (long)row * DIM + kc * 64 + gc, sB + u * 8);
    }
    __syncthreads();
#pragma unroll
    for (int kk = 0; kk < 4; ++kk) {
      const int cc = kk * 2 + half;
      short8 af[2], bf[2];
#pragma unroll
      for (int mt = 0; mt < 2; ++mt) {
        int r = r0 + mt * 32 + ln;
        af[mt] = ld_frag8(sA + r * 64 + (cc ^ (r & 7)) * 8);
      }
#pragma unroll
      for (int nt = 0; nt < 2; ++nt) {
        int r = c0 + nt * 32 + ln;
        bf[nt] = ld_frag8(sB + r * 64 + (cc ^ (r & 7)) * 8);
      }
#pragma unroll
      for (int mt = 0; mt < 2; ++mt)
#pragma unroll
        for (int nt = 0; nt < 2; ++nt)
          acc[mt][nt] = __builtin_amdgcn_mfma_f32_32x32x16_bf16(af[mt], bf[nt], acc[mt][nt], 0, 0, 0);
    }
    __syncthreads();
  }

  // ---- p = exp(s^2 - 1), in place (fp32) ----
#pragma unroll
  for (int mt = 0; mt < 2; ++mt)
#pragma unroll
    for (int nt = 0; nt < 2; ++nt)
#pragma unroll
      for (int r = 0; r < 16; ++r) {
        float s = acc[mt][nt][r];
        acc[mt][nt][r] = __expf(__builtin_fmaf(s, s, -1.0f));
      }

  // ---- row sums (rows i0..) ; col sums (rows j0.. by symmetry) -> atomics into lw ----
  float* lwb = lw + b * SEQ;
  {
    float rs[2][16];
#pragma unroll
    for (int mt = 0; mt < 2; ++mt)
#pragma unroll
      for (int r = 0; r < 16; ++r) {
        float s = acc[mt][0][r] + acc[mt][1][r];
        s += __shfl_xor(s, 1);
        s += __shfl_xor(s, 2);
        s += __shfl_xor(s, 4);
        s += __shfl_xor(s, 8);
        s += __shfl_xor(s, 16);
        rs[mt][r] = s;
      }
    if (ln == 0) {
#pragma unroll
      for (int mt = 0; mt < 2; ++mt)
#pragma unroll
        for (int r = 0; r < 16; ++r) {
          int row = r0 + mt * 32 + (r & 3) + 8 * (r >> 2) + 4 * half;
          atomicAdd(&lwb[i0 + row], rs[mt][r]);
        }
    }
    if (ti != tj) {
#pragma unroll
      for (int nt = 0; nt < 2; ++nt) {
        float cs = 0.f;
#pragma unroll
        for (int mt = 0; mt < 2; ++mt)
#pragma unroll
          for (int r = 0; r < 16; ++r) cs += acc[mt][nt][r];
        cs += __shfl_xor(cs, 32);
        if (half == 0) atomicAdd(&lwb[j0 + c0 + nt * 32 + ln], cs);
      }
    }
  }

  // ---- sQ[col][row] (pitch 136), packed ds_write_b64 over row-quads ----
  unsigned short* sQ = smem;
#pragma unroll
  for (int mt = 0; mt < 2; ++mt)
#pragma unroll
    for (int nt = 0; nt < 2; ++nt) {
      const int col = c0 + nt * 32 + ln;
#pragma unroll
      for (int q = 0; q < 4; ++q) {
        ushort4 wv;
        wv.x = f32_bf16(acc[mt][nt][q * 4 + 0]);
        wv.y = f32_bf16(acc[mt][nt][q * 4 + 1]);
        wv.z = f32_bf16(acc[mt][nt][q * 4 + 2]);
        wv.w = f32_bf16(acc[mt][nt][q * 4 + 3]);
        *reinterpret_cast<ushort4*>(&sQ[col * 136 + r0 + mt * 32 + q * 8 + 4 * half]) = wv;
      }
    }
  __syncthreads();

  unsigned short* Pg = P + (long)b * SEQ * SEQ;
  // row-major tile store: P[i0+row][j0+col] (gather cols from sQ)
#pragma unroll
  for (int k = 0; k < 8; ++k) {
    int u = tid + k * 256;
    int row = u >> 4, c16 = u & 15;
    unsigned short tmp[8];
#pragma unroll
    for (int cc = 0; cc < 8; ++cc) tmp[cc] = sQ[(c16 * 8 + cc) * 136 + row];
    uint4 o;
    o.x = (unsigned)tmp[0] | ((unsigned)tmp[1] << 16);
    o.y = (unsigned)tmp[2] | ((unsigned)tmp[3] << 16);
    o.z = (unsigned)tmp[4] | ((unsigned)tmp[5] << 16);
    o.w = (unsigned)tmp[6] | ((unsigned)tmp[7] << 16);
    *reinterpret_cast<uint4*>(Pg + (long)(i0 + row) * SEQ + j0 + c16 * 8) = o;
  }
  // mirrored tile store: P[j0+col][i0+row] (vector reads, rows of sQ)
  if (ti != tj) {
#pragma unroll
    for (int k = 0; k < 8; ++k) {
      int u = tid + k * 256;
      int jr = u >> 4, c16 = u & 15;
      *reinterpret_cast<uint4*>(Pg + (long)(j0 + jr) * SEQ + i0 + c16 * 8) =
          *reinterpret_cast<const uint4*>(&sQ[jr * 136 + c16 * 8]);
    }
  }
}

// ---------------- gemm2: out[b,i,d] = (P . x) / l ; BK=128, 64KB LDS ----------------
// grid 512 = 8 batches x 16 i-tiles x 4 d-tiles ; 256 threads = 4 waves
__global__ __launch_bounds__(256, 2) void gemm2_kernel(const unsigned short* __restrict__ P,
                                                       const unsigned short* __restrict__ xt,
                                                       const float* __restrict__ l,
                                                       float* __restrict__ out) {
  const int b  = blockIdx.x & 7;
  const int t  = blockIdx.x >> 3;
  const int i0 = (t & 15) * 128;
  const int n0 = (t >> 4) * 128;
  const int tid  = threadIdx.x;
  const int w    = tid >> 6;
  const int lane = tid & 63;
  const int ln   = lane & 31;
  const int half = lane >> 5;

  __shared__ __align__(16) unsigned short sA[16384];   // 128 x 128 bf16 = 32 KB
  __shared__ __align__(16) unsigned short sB[16384];

  const unsigned short* Ag = P  + (long)b * SEQ * SEQ + (long)i0 * SEQ;
  const unsigned short* Bg = xt + (long)b * DIM * SEQ + (long)n0 * SEQ;

  floatx16 acc[2][2];
#pragma unroll
  for (int mt = 0; mt < 2; ++mt)
#pragma unroll
    for (int nt = 0; nt < 2; ++nt)
#pragma unroll
      for (int i = 0; i < 16; ++i) acc[mt][nt][i] = 0.f;

  const int r0 = (w >> 1) * 64;
  const int c0 = (w & 1) * 64;

  for (int kc = 0; kc < 16; ++kc) {
#pragma unroll
    for (int k = 0; k < 8; ++k) {
      int u = tid + k * 256;
      int row = u >> 4, c = u & 15;
      int gc = (c ^ (row & 15)) * 8;
      gld_lds16(Ag + (long)row * SEQ + kc * 128 + gc, sA + u * 8);
      gld_lds16(Bg + (long)row * SEQ + kc * 128 + gc, sB + u * 8);
    }
    __syncthreads();
#pragma unroll
    for (int kk = 0; kk < 8; ++kk) {
      const int cc = kk * 2 + half;
      short8 af[2], bf[2];
#pragma unroll
      for (int mt = 0; mt < 2; ++mt) {
        int r = r0 + mt * 32 + ln;
        af[mt] = ld_frag8(sA + r * 128 + ((cc ^ (r & 15)) * 8));
      }
#pragma unroll
      for (int nt = 0; nt < 2; ++nt) {
        int r = c0 + nt * 32 + ln;
        bf[nt] = ld_frag8(sB + r * 128 + ((cc ^ (r & 15)) * 8));
      }
#pragma unroll
      for (int mt = 0; mt < 2; ++mt)
#pragma unroll
        for (int nt = 0; nt < 2; ++nt)
          acc[mt][nt] = __builtin_amdgcn_mfma_f32_32x32x16_bf16(af[mt], bf[nt], acc[mt][nt], 0, 0, 0);
    }
    __syncthreads();
  }

  // epilogue: divide by l (L2-hot broadcast loads), coalesced fp32 stores
  const float* lb = l + b * SEQ + i0;
  float* outb = out + (long)b * SEQ * DIM;
#pragma unroll
  for (int mt = 0; mt < 2; ++mt)
#pragma unroll
    for (int r = 0; r < 16; ++r) {
      const int row = r0 + mt * 32 + (r & 3) + 8 * (r >> 2) + 4 * half;
      const float inv = 1.0f / lb[row];
#pragma unroll
      for (int nt = 0; nt < 2; ++nt) {
        const int col = c0 + nt * 32 + ln;
        outb[(long)(i0 + row) * DIM + n0 + col] = acc[mt][nt][r] * inv;
      }
    }
}

extern "C" void kernel_launch(void* const* d_in, const int* in_sizes, int n_in,
                              void* d_out, int out_size, void* d_ws, size_t ws_size,
                              hipStream_t stream) {
  const float* x = (const float*)d_in[0];
  float* outp = (float*)d_out;

  unsigned short* xn = (unsigned short*)d_ws;                        // 16.78 MB
  unsigned short* xt = xn + (size_t)BATCH * SEQ * DIM;               // 16.78 MB
  unsigned short* Pw = xt + (size_t)BATCH * SEQ * DIM;               // 67.1 MB
  float*          lw = (float*)(Pw + (size_t)BATCH * SEQ * SEQ);     // 64 KB

  hipMemsetAsync(lw, 0, (size_t)BATCH * SEQ * sizeof(float), stream);
  prep_kernel <<<BATCH * (SEQ / 32), 256, 0, stream>>>(x, xn, xt);
  gemm1_kernel<<<BATCH * 136,        256, 0, stream>>>(xn, Pw, lw);
  gemm2_kernel<<<BATCH * 16 * 4,     256, 0, stream>>>(Pw, xt, lw, outp);
}

// Round 4
// 181.334 us; speedup vs baseline: 1.0035x; 1.0035x over previous
//
#include <hip/hip_runtime.h>
#include <stdint.h>

#define BATCH 8
#define SEQ   2048
#define DIM   512

typedef __attribute__((ext_vector_type(8)))  short short8;    // 8 bf16 (4 VGPRs)
typedef __attribute__((ext_vector_type(16))) float floatx16;  // 32x32 C/D frag

static __device__ __forceinline__ unsigned short f32_bf16(float f) {
  unsigned u = __builtin_bit_cast(unsigned, f);
  u += 0x7FFFu + ((u >> 16) & 1u);          // round-to-nearest-even
  return (unsigned short)(u >> 16);
}
static __device__ __forceinline__ unsigned pack2(float a, float b) {
  return (unsigned)f32_bf16(a) | ((unsigned)f32_bf16(b) << 16);
}
static __device__ __forceinline__ short8 ld_frag8(const unsigned short* p) {
  return __builtin_bit_cast(short8, *reinterpret_cast<const uint4*>(p));
}
static __device__ __forceinline__ void gld_lds16(const unsigned short* g, unsigned short* l) {
  __builtin_amdgcn_global_load_lds((const __attribute__((address_space(1))) unsigned int*)g,
                                   (__attribute__((address_space(3))) unsigned int*)l, 16, 0, 0);
}

// ---------------- prep: x -> xn (bf16 x-hat, row-major) and xt (bf16 x^T, [b][d][j]) --------
// grid 1024 = 8 batches x 128 j-blocks of 16 rows ; 256 threads ; high occupancy
__global__ __launch_bounds__(256) void prep_kernel(const float* __restrict__ x,
                                                   unsigned short* __restrict__ xn,
                                                   unsigned short* __restrict__ xt) {
  const int b  = blockIdx.x >> 7;
  const int jb = blockIdx.x & 127;
  const int t  = threadIdx.x;
  const int j  = t >> 4;   // 0..15 row in tile
  const int s  = t & 15;   // 0..15 segment of 32 elems

  __shared__ unsigned short xs[16 * 512];   // bf16(x) tile, XOR-swizzled 16B chunks

  const long rowg = ((long)b * SEQ + (long)jb * 16 + j) * DIM;
  const float4* xv = reinterpret_cast<const float4*>(x + rowg + s * 32);
  float4 v[8];
  float acc = 0.f;
#pragma unroll
  for (int k = 0; k < 8; ++k) {
    v[k] = xv[k];
    acc += v[k].x*v[k].x + v[k].y*v[k].y + v[k].z*v[k].z + v[k].w*v[k].w;
  }
  // butterfly over the 16-lane j-group (masks <16 stay in group)
  acc += __shfl_xor(acc, 1);
  acc += __shfl_xor(acc, 2);
  acc += __shfl_xor(acc, 4);
  acc += __shfl_xor(acc, 8);
  const float sc = 1.f / (sqrtf(acc) + 1e-12f);

  unsigned short* xnp = xn + rowg + s * 32;
#pragma unroll
  for (int k = 0; k < 4; ++k) {           // 4 x 16B = 32 bf16
    float4 a = v[2*k], c = v[2*k+1];
    uint4 on;                              // normalized -> xn
    on.x = pack2(a.x*sc, a.y*sc); on.y = pack2(a.z*sc, a.w*sc);
    on.z = pack2(c.x*sc, c.y*sc); on.w = pack2(c.z*sc, c.w*sc);
    *reinterpret_cast<uint4*>(xnp + k * 8) = on;
    uint4 ou;                              // unscaled -> xs (for x^T)
    ou.x = pack2(a.x, a.y); ou.y = pack2(a.z, a.w);
    ou.z = pack2(c.x, c.y); ou.w = pack2(c.z, c.w);
    const int c16 = (s * 4 + k) ^ (j & 7); // XOR-swizzled chunk
    *reinterpret_cast<uint4*>(&xs[j * 512 + c16 * 8]) = ou;
  }
  __syncthreads();

  unsigned short* xtb = xt + (long)b * DIM * SEQ;
#pragma unroll
  for (int u = t; u < 1024; u += 256) {    // 512 d-rows x 2 j-octants
    const int d = u >> 1, jh = u & 1;
    const int ch = d >> 3, e = d & 7;
    unsigned short tmp[8];
#pragma unroll
    for (int r = 0; r < 8; ++r) {
      const int j2 = jh * 8 + r;
      tmp[r] = xs[j2 * 512 + ((ch ^ (j2 & 7)) * 8) + e];
    }
    uint4 o;
    o.x = (unsigned)tmp[0] | ((unsigned)tmp[1] << 16);
    o.y = (unsigned)tmp[2] | ((unsigned)tmp[3] << 16);
    o.z = (unsigned)tmp[4] | ((unsigned)tmp[5] << 16);
    o.w = (unsigned)tmp[6] | ((unsigned)tmp[7] << 16);
    *reinterpret_cast<uint4*>(xtb + (long)d * SEQ + jb * 16 + jh * 8) = o;
  }
}

// ---------------- gemm1: P[b,i,j] = bf16(exp(S^2-1)), S = xn.xn^T ; fused row sums -------
// grid 2048 = 8 batches x 16 i-tiles x 16 j-tiles ; 256 threads = 4 waves
__global__ __launch_bounds__(256, 3) void gemm1_kernel(const unsigned short* __restrict__ xn,
                                                       unsigned short* __restrict__ P,
                                                       float* __restrict__ lw) {
  const int b  = blockIdx.x & 7;
  const int t  = blockIdx.x >> 3;
  const int i0 = (t & 15) * 128;
  const int j0 = (t >> 4) * 128;
  const int tid  = threadIdx.x;
  const int w    = tid >> 6;
  const int lane = tid & 63;
  const int ln   = lane & 31;
  const int half = lane >> 5;

  __shared__ __align__(16) unsigned short smem[17408];   // staging 32KB ; epilogue sP 128x136
  unsigned short* sA = smem;
  unsigned short* sB = smem + 8192;

  const unsigned short* xb = xn + (long)b * SEQ * DIM;
  const unsigned short* Ag = xb + (long)i0 * DIM;
  const unsigned short* Bg = xb + (long)j0 * DIM;

  floatx16 acc[2][2];
#pragma unroll
  for (int mt = 0; mt < 2; ++mt)
#pragma unroll
    for (int nt = 0; nt < 2; ++nt)
#pragma unroll
      for (int i = 0; i < 16; ++i) acc[mt][nt][i] = 0.f;

  const int r0 = (w >> 1) * 64;
  const int c0 = (w & 1) * 64;

  for (int kc = 0; kc < 8; ++kc) {
#pragma unroll
    for (int k = 0; k < 4; ++k) {
      int u = tid + k * 256;
      int row = u >> 3, c = u & 7;
      int gc = (c ^ (row & 7)) * 8;
      gld_lds16(Ag + (long)row * DIM + kc * 64 + gc, sA + u * 8);
      gld_lds16(Bg + (long)row * DIM + kc * 64 + gc, sB + u * 8);
    }
    __syncthreads();
#pragma unroll
    for (int kk = 0; kk < 4; ++kk) {
      const int cc = kk * 2 + half;
      short8 af[2], bf[2];
#pragma unroll
      for (int mt = 0; mt < 2; ++mt) {
        int r = r0 + mt * 32 + ln;
        af[mt] = ld_frag8(sA + r * 64 + (cc ^ (r & 7)) * 8);
      }
#pragma unroll
      for (int nt = 0; nt < 2; ++nt) {
        int r = c0 + nt * 32 + ln;
        bf[nt] = ld_frag8(sB + r * 64 + (cc ^ (r & 7)) * 8);
      }
#pragma unroll
      for (int mt = 0; mt < 2; ++mt)
#pragma unroll
        for (int nt = 0; nt < 2; ++nt)
          acc[mt][nt] = __builtin_amdgcn_mfma_f32_32x32x16_bf16(af[mt], bf[nt], acc[mt][nt], 0, 0, 0);
    }
    __syncthreads();
  }

  // ---- p = exp(s^2 - 1) in place (fp32) ----
#pragma unroll
  for (int mt = 0; mt < 2; ++mt)
#pragma unroll
    for (int nt = 0; nt < 2; ++nt)
#pragma unroll
      for (int r = 0; r < 16; ++r) {
        float s = acc[mt][nt][r];
        acc[mt][nt][r] = __expf(__builtin_fmaf(s, s, -1.0f));
      }

  // ---- fused row sums: butterfly over 32 cols (x2 nt in-register), atomics into lw ----
  float* lwb = lw + b * SEQ + i0;
#pragma unroll
  for (int mt = 0; mt < 2; ++mt) {
    float rs[16];
#pragma unroll
    for (int r = 0; r < 16; ++r) {
      float s = acc[mt][0][r] + acc[mt][1][r];
      s += __shfl_xor(s, 1);
      s += __shfl_xor(s, 2);
      s += __shfl_xor(s, 4);
      s += __shfl_xor(s, 8);
      s += __shfl_xor(s, 16);
      rs[r] = s;
    }
    if (ln == 0) {
#pragma unroll
      for (int r = 0; r < 16; ++r) {
        int row = r0 + mt * 32 + (r & 3) + 8 * (r >> 2) + 4 * half;
        atomicAdd(&lwb[row], rs[r]);
      }
    }
  }

  // ---- sP[row][col] pitch 136 (conflict-free), coalesced bf16 stores ----
  unsigned short* sP = smem;
#pragma unroll
  for (int mt = 0; mt < 2; ++mt)
#pragma unroll
    for (int nt = 0; nt < 2; ++nt) {
      const int col = c0 + nt * 32 + ln;
#pragma unroll
      for (int r = 0; r < 16; ++r) {
        int row = r0 + mt * 32 + (r & 3) + 8 * (r >> 2) + 4 * half;
        sP[row * 136 + col] = f32_bf16(acc[mt][nt][r]);
      }
    }
  __syncthreads();
  unsigned short* Pg = P + (long)b * SEQ * SEQ;
#pragma unroll
  for (int k = 0; k < 8; ++k) {
    int u = tid + k * 256;
    int row = u >> 4, c16 = u & 15;
    *reinterpret_cast<uint4*>(Pg + (long)(i0 + row) * SEQ + j0 + c16 * 8) =
        *reinterpret_cast<const uint4*>(sP + row * 136 + c16 * 8);
  }
}

// ---------------- gemm2: out[b,i,d] = (P . x) / l ; BK=64 (proven round-2 config) --------
// grid 512 = 8 batches x 16 i-tiles x 4 d-tiles ; 256 threads = 4 waves
__global__ __launch_bounds__(256, 3) void gemm2_kernel(const unsigned short* __restrict__ P,
                                                       const unsigned short* __restrict__ xt,
                                                       const float* __restrict__ l,
                                                       float* __restrict__ out) {
  const int b  = blockIdx.x & 7;
  const int t  = blockIdx.x >> 3;
  const int i0 = (t & 15) * 128;
  const int n0 = (t >> 4) * 128;
  const int tid  = threadIdx.x;
  const int w    = tid >> 6;
  const int lane = tid & 63;
  const int ln   = lane & 31;
  const int half = lane >> 5;

  __shared__ __align__(16) unsigned short sA[8192];
  __shared__ __align__(16) unsigned short sB[8192];
  __shared__ float sl[128];

  const unsigned short* Ag = P  + (long)b * SEQ * SEQ + (long)i0 * SEQ;
  const unsigned short* Bg = xt + (long)b * DIM * SEQ + (long)n0 * SEQ;

  if (tid < 128) sl[tid] = l[b * SEQ + i0 + tid];

  floatx16 acc[2][2];
#pragma unroll
  for (int mt = 0; mt < 2; ++mt)
#pragma unroll
    for (int nt = 0; nt < 2; ++nt)
#pragma unroll
      for (int i = 0; i < 16; ++i) acc[mt][nt][i] = 0.f;

  const int r0 = (w >> 1) * 64;
  const int c0 = (w & 1) * 64;

  for (int kc = 0; kc < 32; ++kc) {
#pragma unroll
    for (int k = 0; k < 4; ++k) {
      int u = tid + k * 256;
      int row = u >> 3, c = u & 7;
      int gc = (c ^ (row & 7)) * 8;
      gld_lds16(Ag + (long)row * SEQ + kc * 64 + gc, sA + u * 8);
      gld_lds16(Bg + (long)row * SEQ + kc * 64 + gc, sB + u * 8);
    }
    __syncthreads();
#pragma unroll
    for (int kk = 0; kk < 4; ++kk) {
      const int cc = kk * 2 + half;
      short8 af[2], bf[2];
#pragma unroll
      for (int mt = 0; mt < 2; ++mt) {
        int r = r0 + mt * 32 + ln;
        af[mt] = ld_frag8(sA + r * 64 + (cc ^ (r & 7)) * 8);
      }
#pragma unroll
      for (int nt = 0; nt < 2; ++nt) {
        int r = c0 + nt * 32 + ln;
        bf[nt] = ld_frag8(sB + r * 64 + (cc ^ (r & 7)) * 8);
      }
#pragma unroll
      for (int mt = 0; mt < 2; ++mt)
#pragma unroll
        for (int nt = 0; nt < 2; ++nt)
          acc[mt][nt] = __builtin_amdgcn_mfma_f32_32x32x16_bf16(af[mt], bf[nt], acc[mt][nt], 0, 0, 0);
    }
    __syncthreads();
  }

  // epilogue: divide by l, coalesced fp32 stores
  float* outb = out + (long)b * SEQ * DIM;
#pragma unroll
  for (int mt = 0; mt < 2; ++mt)
#pragma unroll
    for (int r = 0; r < 16; ++r) {
      const int row = r0 + mt * 32 + (r & 3) + 8 * (r >> 2) + 4 * half;
      const float inv = 1.0f / sl[row];
#pragma unroll
      for (int nt = 0; nt < 2; ++nt) {
        const int col = c0 + nt * 32 + ln;
        outb[(long)(i0 + row) * DIM + n0 + col] = acc[mt][nt][r] * inv;
      }
    }
}

extern "C" void kernel_launch(void* const* d_in, const int* in_sizes, int n_in,
                              void* d_out, int out_size, void* d_ws, size_t ws_size,
                              hipStream_t stream) {
  const float* x = (const float*)d_in[0];
  float* outp = (float*)d_out;

  unsigned short* xn = (unsigned short*)d_ws;                        // 16.78 MB
  unsigned short* xt = xn + (size_t)BATCH * SEQ * DIM;               // 16.78 MB
  unsigned short* Pw = xt + (size_t)BATCH * SEQ * DIM;               // 67.1 MB
  float*          lw = (float*)(Pw + (size_t)BATCH * SEQ * SEQ);     // 64 KB

  hipMemsetAsync(lw, 0, (size_t)BATCH * SEQ * sizeof(float), stream);
  prep_kernel <<<BATCH * (SEQ / 16), 256, 0, stream>>>(x, xn, xt);
  gemm1_kernel<<<BATCH * 16 * 16,    256, 0, stream>>>(xn, Pw, lw);
  gemm2_kernel<<<BATCH * 16 * 4,     256, 0, stream>>>(Pw, xt, lw, outp);
}

// Round 5
// 170.469 us; speedup vs baseline: 1.0675x; 1.0637x over previous
//
#include <hip/hip_runtime.h>
#include <stdint.h>

#define BATCH 8
#define SEQ   2048
#define DIM   512

typedef __attribute__((ext_vector_type(8)))  short short8;    // 8 bf16 (4 VGPRs)
typedef __attribute__((ext_vector_type(16))) float floatx16;  // 32x32 C/D frag

static __device__ __forceinline__ unsigned short f32_bf16(float f) {
  unsigned u = __builtin_bit_cast(unsigned, f);
  u += 0x7FFFu + ((u >> 16) & 1u);          // round-to-nearest-even
  return (unsigned short)(u >> 16);
}
static __device__ __forceinline__ unsigned pack2(float a, float b) {
  return (unsigned)f32_bf16(a) | ((unsigned)f32_bf16(b) << 16);
}
static __device__ __forceinline__ short8 ld_frag8(const unsigned short* p) {
  return __builtin_bit_cast(short8, *reinterpret_cast<const uint4*>(p));
}
static __device__ __forceinline__ void gld_lds16(const unsigned short* g, unsigned short* l) {
  __builtin_amdgcn_global_load_lds((const __attribute__((address_space(1))) unsigned int*)g,
                                   (__attribute__((address_space(3))) unsigned int*)l, 16, 0, 0);
}

// ---------------- prep: x -> xn (bf16 x-hat, row-major) and xt (bf16 x^T, [b][d][j]) --------
// grid 1024 = 128 j-blocks x 8 batches ; b = blockIdx&7 so a batch's jb-blocks share an XCD
// (adjacent jb write adjacent 32B segments of each xt line -> L2 write-merge before HBM)
__global__ __launch_bounds__(256) void prep_kernel(const float* __restrict__ x,
                                                   unsigned short* __restrict__ xn,
                                                   unsigned short* __restrict__ xt) {
  const int b  = blockIdx.x & 7;
  const int jb = blockIdx.x >> 3;
  const int t  = threadIdx.x;
  const int j  = t >> 4;   // 0..15 row in tile
  const int s  = t & 15;   // 0..15 segment of 32 elems

  __shared__ unsigned short xs[16 * 512];   // bf16(x) tile, XOR-swizzled 16B chunks

  const long rowg = ((long)b * SEQ + (long)jb * 16 + j) * DIM;
  const float4* xv = reinterpret_cast<const float4*>(x + rowg + s * 32);
  float4 v[8];
  float acc = 0.f;
#pragma unroll
  for (int k = 0; k < 8; ++k) {
    v[k] = xv[k];
    acc += v[k].x*v[k].x + v[k].y*v[k].y + v[k].z*v[k].z + v[k].w*v[k].w;
  }
  // butterfly over the 16-lane j-group (masks <16 stay in group)
  acc += __shfl_xor(acc, 1);
  acc += __shfl_xor(acc, 2);
  acc += __shfl_xor(acc, 4);
  acc += __shfl_xor(acc, 8);
  const float sc = 1.f / (sqrtf(acc) + 1e-12f);

  unsigned short* xnp = xn + rowg + s * 32;
#pragma unroll
  for (int k = 0; k < 4; ++k) {           // 4 x 16B = 32 bf16
    float4 a = v[2*k], c = v[2*k+1];
    uint4 on;                              // normalized -> xn
    on.x = pack2(a.x*sc, a.y*sc); on.y = pack2(a.z*sc, a.w*sc);
    on.z = pack2(c.x*sc, c.y*sc); on.w = pack2(c.z*sc, c.w*sc);
    *reinterpret_cast<uint4*>(xnp + k * 8) = on;
    uint4 ou;                              // unscaled -> xs (for x^T)
    ou.x = pack2(a.x, a.y); ou.y = pack2(a.z, a.w);
    ou.z = pack2(c.x, c.y); ou.w = pack2(c.z, c.w);
    const int c16 = (s * 4 + k) ^ (j & 7); // XOR-swizzled chunk
    *reinterpret_cast<uint4*>(&xs[j * 512 + c16 * 8]) = ou;
  }
  __syncthreads();

  unsigned short* xtb = xt + (long)b * DIM * SEQ;
#pragma unroll
  for (int u = t; u < 1024; u += 256) {    // 512 d-rows x 2 j-octants
    const int d = u >> 1, jh = u & 1;
    const int ch = d >> 3, e = d & 7;
    unsigned short tmp[8];
#pragma unroll
    for (int r = 0; r < 8; ++r) {
      const int j2 = jh * 8 + r;
      tmp[r] = xs[j2 * 512 + ((ch ^ (j2 & 7)) * 8) + e];
    }
    uint4 o;
    o.x = (unsigned)tmp[0] | ((unsigned)tmp[1] << 16);
    o.y = (unsigned)tmp[2] | ((unsigned)tmp[3] << 16);
    o.z = (unsigned)tmp[4] | ((unsigned)tmp[5] << 16);
    o.w = (unsigned)tmp[6] | ((unsigned)tmp[7] << 16);
    *reinterpret_cast<uint4*>(xtb + (long)d * SEQ + jb * 16 + jh * 8) = o;
  }
}

// ---------------- gemm1: P[b,i,j] = bf16(exp(S^2-1)), S = xn.xn^T (round-2 proven) -------
// grid 2048 = 8 batches x 16 i-tiles x 16 j-tiles ; 256 threads = 4 waves
__global__ __launch_bounds__(256, 3) void gemm1_kernel(const unsigned short* __restrict__ xn,
                                                       unsigned short* __restrict__ P) {
  const int b  = blockIdx.x & 7;
  const int t  = blockIdx.x >> 3;
  const int i0 = (t & 15) * 128;
  const int j0 = (t >> 4) * 128;
  const int tid  = threadIdx.x;
  const int w    = tid >> 6;
  const int lane = tid & 63;
  const int ln   = lane & 31;
  const int half = lane >> 5;

  __shared__ __align__(16) unsigned short smem[17408];   // staging 32KB ; epilogue sP 128x136
  unsigned short* sA = smem;
  unsigned short* sB = smem + 8192;

  const unsigned short* xb = xn + (long)b * SEQ * DIM;
  const unsigned short* Ag = xb + (long)i0 * DIM;
  const unsigned short* Bg = xb + (long)j0 * DIM;

  floatx16 acc[2][2];
#pragma unroll
  for (int mt = 0; mt < 2; ++mt)
#pragma unroll
    for (int nt = 0; nt < 2; ++nt)
#pragma unroll
      for (int i = 0; i < 16; ++i) acc[mt][nt][i] = 0.f;

  const int r0 = (w >> 1) * 64;
  const int c0 = (w & 1) * 64;

  for (int kc = 0; kc < 8; ++kc) {
#pragma unroll
    for (int k = 0; k < 4; ++k) {
      int u = tid + k * 256;
      int row = u >> 3, c = u & 7;
      int gc = (c ^ (row & 7)) * 8;
      gld_lds16(Ag + (long)row * DIM + kc * 64 + gc, sA + u * 8);
      gld_lds16(Bg + (long)row * DIM + kc * 64 + gc, sB + u * 8);
    }
    __syncthreads();
#pragma unroll
    for (int kk = 0; kk < 4; ++kk) {
      const int cc = kk * 2 + half;
      short8 af[2], bf[2];
#pragma unroll
      for (int mt = 0; mt < 2; ++mt) {
        int r = r0 + mt * 32 + ln;
        af[mt] = ld_frag8(sA + r * 64 + (cc ^ (r & 7)) * 8);
      }
#pragma unroll
      for (int nt = 0; nt < 2; ++nt) {
        int r = c0 + nt * 32 + ln;
        bf[nt] = ld_frag8(sB + r * 64 + (cc ^ (r & 7)) * 8);
      }
#pragma unroll
      for (int mt = 0; mt < 2; ++mt)
#pragma unroll
        for (int nt = 0; nt < 2; ++nt)
          acc[mt][nt] = __builtin_amdgcn_mfma_f32_32x32x16_bf16(af[mt], bf[nt], acc[mt][nt], 0, 0, 0);
    }
    __syncthreads();
  }

  // epilogue: p = exp(s^2-1) -> LDS (pitch 136, conflict-free) -> coalesced bf16 stores
  unsigned short* sP = smem;
#pragma unroll
  for (int mt = 0; mt < 2; ++mt)
#pragma unroll
    for (int nt = 0; nt < 2; ++nt) {
      const int col = c0 + nt * 32 + ln;
#pragma unroll
      for (int r = 0; r < 16; ++r) {
        float s = acc[mt][nt][r];
        float p = __expf(__builtin_fmaf(s, s, -1.0f));
        int row = r0 + mt * 32 + (r & 3) + 8 * (r >> 2) + 4 * half;
        sP[row * 136 + col] = f32_bf16(p);
      }
    }
  __syncthreads();
  unsigned short* Pg = P + (long)b * SEQ * SEQ;
#pragma unroll
  for (int k = 0; k < 8; ++k) {
    int u = tid + k * 256;
    int row = u >> 4, c16 = u & 15;
    *reinterpret_cast<uint4*>(Pg + (long)(i0 + row) * SEQ + j0 + c16 * 8) =
        *reinterpret_cast<const uint4*>(sP + row * 136 + c16 * 8);
  }
}

// ---------------- gemm2: out[b,i,d] = (P . x) / l ; l computed in-register via ones-MFMA --
// Every block loads the FULL K=2048 rows of P as A-fragments, so l (row sums of P) is
// computed locally: l_acc = mfma(af, ones) accumulated over the whole K loop. No atomics,
// no workspace, and l_acc's C/D row mapping matches o_acc's exactly -> divide in-register.
// grid 512 = 8 batches x 16 i-tiles x 4 d-tiles ; 256 threads = 4 waves
__global__ __launch_bounds__(256, 3) void gemm2_kernel(const unsigned short* __restrict__ P,
                                                       const unsigned short* __restrict__ xt,
                                                       float* __restrict__ out) {
  const int b  = blockIdx.x & 7;
  const int t  = blockIdx.x >> 3;
  const int i0 = (t & 15) * 128;
  const int n0 = (t >> 4) * 128;
  const int tid  = threadIdx.x;
  const int w    = tid >> 6;
  const int lane = tid & 63;
  const int ln   = lane & 31;
  const int half = lane >> 5;

  __shared__ __align__(16) unsigned short sA[8192];
  __shared__ __align__(16) unsigned short sB[8192];

  const unsigned short* Ag = P  + (long)b * SEQ * SEQ + (long)i0 * SEQ;
  const unsigned short* Bg = xt + (long)b * DIM * SEQ + (long)n0 * SEQ;

  floatx16 acc[2][2];
  floatx16 l_acc[2];
#pragma unroll
  for (int mt = 0; mt < 2; ++mt) {
#pragma unroll
    for (int i = 0; i < 16; ++i) l_acc[mt][i] = 0.f;
#pragma unroll
    for (int nt = 0; nt < 2; ++nt)
#pragma unroll
      for (int i = 0; i < 16; ++i) acc[mt][nt][i] = 0.f;
  }
  short8 ones;
#pragma unroll
  for (int i = 0; i < 8; ++i) ones[i] = (short)0x3F80;   // bf16 1.0

  const int r0 = (w >> 1) * 64;
  const int c0 = (w & 1) * 64;

  for (int kc = 0; kc < 32; ++kc) {
#pragma unroll
    for (int k = 0; k < 4; ++k) {
      int u = tid + k * 256;
      int row = u >> 3, c = u & 7;
      int gc = (c ^ (row & 7)) * 8;
      gld_lds16(Ag + (long)row * SEQ + kc * 64 + gc, sA + u * 8);
      gld_lds16(Bg + (long)row * SEQ + kc * 64 + gc, sB + u * 8);
    }
    __syncthreads();
#pragma unroll
    for (int kk = 0; kk < 4; ++kk) {
      const int cc = kk * 2 + half;
      short8 af[2], bf[2];
#pragma unroll
      for (int mt = 0; mt < 2; ++mt) {
        int r = r0 + mt * 32 + ln;
        af[mt] = ld_frag8(sA + r * 64 + (cc ^ (r & 7)) * 8);
      }
#pragma unroll
      for (int nt = 0; nt < 2; ++nt) {
        int r = c0 + nt * 32 + ln;
        bf[nt] = ld_frag8(sB + r * 64 + (cc ^ (r & 7)) * 8);
      }
#pragma unroll
      for (int mt = 0; mt < 2; ++mt)
#pragma unroll
        for (int nt = 0; nt < 2; ++nt)
          acc[mt][nt] = __builtin_amdgcn_mfma_f32_32x32x16_bf16(af[mt], bf[nt], acc[mt][nt], 0, 0, 0);
#pragma unroll
      for (int mt = 0; mt < 2; ++mt)
        l_acc[mt] = __builtin_amdgcn_mfma_f32_32x32x16_bf16(af[mt], ones, l_acc[mt], 0, 0, 0);
    }
    __syncthreads();
  }

  // epilogue: divide by in-register row sums, coalesced fp32 stores
  float* outb = out + (long)b * SEQ * DIM;
#pragma unroll
  for (int mt = 0; mt < 2; ++mt)
#pragma unroll
    for (int r = 0; r < 16; ++r) {
      const int row = r0 + mt * 32 + (r & 3) + 8 * (r >> 2) + 4 * half;
      const float inv = 1.0f / l_acc[mt][r];
#pragma unroll
      for (int nt = 0; nt < 2; ++nt) {
        const int col = c0 + nt * 32 + ln;
        outb[(long)(i0 + row) * DIM + n0 + col] = acc[mt][nt][r] * inv;
      }
    }
}

extern "C" void kernel_launch(void* const* d_in, const int* in_sizes, int n_in,
                              void* d_out, int out_size, void* d_ws, size_t ws_size,
                              hipStream_t stream) {
  const float* x = (const float*)d_in[0];
  float* outp = (float*)d_out;

  unsigned short* xn = (unsigned short*)d_ws;                        // 16.78 MB
  unsigned short* xt = xn + (size_t)BATCH * SEQ * DIM;               // 16.78 MB
  unsigned short* Pw = xt + (size_t)BATCH * SEQ * DIM;               // 67.1 MB

  prep_kernel <<<BATCH * (SEQ / 16), 256, 0, stream>>>(x, xn, xt);
  gemm1_kernel<<<BATCH * 16 * 16,    256, 0, stream>>>(xn, Pw);
  gemm2_kernel<<<BATCH * 16 * 4,     256, 0, stream>>>(Pw, xt, outp);
}

// Round 6
// 168.831 us; speedup vs baseline: 1.0778x; 1.0097x over previous
//
#include <hip/hip_runtime.h>
#include <stdint.h>

#define BATCH 8
#define SEQ   2048
#define DIM   512

typedef __attribute__((ext_vector_type(8)))  short short8;    // 8 bf16 (4 VGPRs)
typedef __attribute__((ext_vector_type(16))) float floatx16;  // 32x32 C/D frag

static __device__ __forceinline__ unsigned short f32_bf16(float f) {
  unsigned u = __builtin_bit_cast(unsigned, f);
  u += 0x7FFFu + ((u >> 16) & 1u);          // round-to-nearest-even
  return (unsigned short)(u >> 16);
}
static __device__ __forceinline__ short8 ld_frag8(const unsigned short* p) {
  return __builtin_bit_cast(short8, *reinterpret_cast<const uint4*>(p));
}
static __device__ __forceinline__ void gld_lds16(const unsigned short* g, unsigned short* l) {
  __builtin_amdgcn_global_load_lds((const __attribute__((address_space(1))) unsigned int*)g,
                                   (__attribute__((address_space(3))) unsigned int*)l, 16, 0, 0);
}
static __device__ __forceinline__ float bf_lo(unsigned u) {
  return __builtin_bit_cast(float, u << 16);
}
static __device__ __forceinline__ float bf_hi(unsigned u) {
  return __builtin_bit_cast(float, u & 0xFFFF0000u);
}

// ---------------- prep: x -> xn (bf16 x-hat, row-major) and xt (bf16 x^T, [b][d][j]) --------
// grid 256 = 8 batches (XCD-pinned via &7) x 32 j-tiles of 64 rows ; 512 threads.
// Whole row held in registers (64 f32/thread): norm + xn need no LDS; xt via [d][j] LDS
// (pitch 66: scalar writes 2-way/free, b32 gathers uniform 2-way/free, stores 8x128B lines).
__global__ __launch_bounds__(512) void prep_kernel(const float* __restrict__ x,
                                                   unsigned short* __restrict__ xn,
                                                   unsigned short* __restrict__ xt) {
  const int b   = blockIdx.x & 7;
  const int jt  = blockIdx.x >> 3;     // 0..31
  const int t   = threadIdx.x;         // 0..511
  const int row = t >> 3;              // 0..63
  const int oct = t & 7;               // 0..7

  __shared__ unsigned short xs[512 * 66];   // [d][j] bf16, pitch 66 u16 (66 KB)

  const long rowg = ((long)b * SEQ + jt * 64 + row) * DIM;
  const float* xp = x + rowg;

  float4 v[16];
#pragma unroll
  for (int k = 0; k < 16; ++k)
    v[k] = *reinterpret_cast<const float4*>(xp + k * 32 + oct * 4);

  float acc = 0.f;
#pragma unroll
  for (int k = 0; k < 16; ++k)
    acc += v[k].x*v[k].x + v[k].y*v[k].y + v[k].z*v[k].z + v[k].w*v[k].w;
  acc += __shfl_xor(acc, 1);
  acc += __shfl_xor(acc, 2);
  acc += __shfl_xor(acc, 4);
  const float sc = 1.f / (sqrtf(acc) + 1e-12f);

  // xn straight from registers (8B/lane, pairs of instrs form full 128B lines)
  unsigned short* xnp = xn + rowg + oct * 4;
#pragma unroll
  for (int k = 0; k < 16; ++k) {
    ushort4 pk;
    pk.x = f32_bf16(v[k].x * sc); pk.y = f32_bf16(v[k].y * sc);
    pk.z = f32_bf16(v[k].z * sc); pk.w = f32_bf16(v[k].w * sc);
    *reinterpret_cast<ushort4*>(xnp + k * 32) = pk;
  }

  // LDS transpose staging: scalar u16 writes, bank = (4*oct + m + row/2) % 32 -> 2-way/free
#pragma unroll
  for (int k = 0; k < 16; ++k) {
    const int d = k * 32 + oct * 4;
    xs[(d + 0) * 66 + row] = f32_bf16(v[k].x);
    xs[(d + 1) * 66 + row] = f32_bf16(v[k].y);
    xs[(d + 2) * 66 + row] = f32_bf16(v[k].z);
    xs[(d + 3) * 66 + row] = f32_bf16(v[k].w);
  }
  __syncthreads();

  // xt: per instr 8 consecutive d-rows x 64 j = 8 full 128B lines
  unsigned short* xtb = xt + (long)b * DIM * SEQ + jt * 64;
  const int wv = t >> 6, li = t & 63, dsub = li >> 3, jc = li & 7;
#pragma unroll
  for (int it = 0; it < 8; ++it) {
    const int d = (it * 8 + wv) * 8 + dsub;
    const unsigned* bse = reinterpret_cast<const unsigned*>(&xs[d * 66 + jc * 8]);
    uint4 o;
    o.x = bse[0]; o.y = bse[1]; o.z = bse[2]; o.w = bse[3];   // 4 x ds_read_b32, 2-way/free
    *reinterpret_cast<uint4*>(xtb + (long)d * SEQ + jc * 8) = o;
  }
}

// ---------------- gemm1: P[b,i,j] = bf16(exp(S^2-1)), S = xn.xn^T ; fused cheap partials --
// grid 2048 = 8 batches x 16 i x 16 j ; 256 threads = 4 waves
__global__ __launch_bounds__(256, 3) void gemm1_kernel(const unsigned short* __restrict__ xn,
                                                       unsigned short* __restrict__ P,
                                                       float* __restrict__ lw) {
  const int b  = blockIdx.x & 7;
  const int t  = blockIdx.x >> 3;
  const int i0 = (t & 15) * 128;
  const int j0 = (t >> 4) * 128;
  const int tid  = threadIdx.x;
  const int w    = tid >> 6;
  const int lane = tid & 63;
  const int ln   = lane & 31;
  const int half = lane >> 5;

  __shared__ __align__(16) unsigned short smem[17408];   // staging 32KB ; epilogue sP 128x136
  unsigned short* sA = smem;
  unsigned short* sB = smem + 8192;

  const unsigned short* xb = xn + (long)b * SEQ * DIM;
  const unsigned short* Ag = xb + (long)i0 * DIM;
  const unsigned short* Bg = xb + (long)j0 * DIM;

  floatx16 acc[2][2];
#pragma unroll
  for (int mt = 0; mt < 2; ++mt)
#pragma unroll
    for (int nt = 0; nt < 2; ++nt)
#pragma unroll
      for (int i = 0; i < 16; ++i) acc[mt][nt][i] = 0.f;

  const int r0 = (w >> 1) * 64;
  const int c0 = (w & 1) * 64;

  for (int kc = 0; kc < 8; ++kc) {
#pragma unroll
    for (int k = 0; k < 4; ++k) {
      int u = tid + k * 256;
      int row = u >> 3, c = u & 7;
      int gc = (c ^ (row & 7)) * 8;
      gld_lds16(Ag + (long)row * DIM + kc * 64 + gc, sA + u * 8);
      gld_lds16(Bg + (long)row * DIM + kc * 64 + gc, sB + u * 8);
    }
    __syncthreads();
#pragma unroll
    for (int kk = 0; kk < 4; ++kk) {
      const int cc = kk * 2 + half;
      short8 af[2], bf[2];
#pragma unroll
      for (int mt = 0; mt < 2; ++mt) {
        int r = r0 + mt * 32 + ln;
        af[mt] = ld_frag8(sA + r * 64 + (cc ^ (r & 7)) * 8);
      }
#pragma unroll
      for (int nt = 0; nt < 2; ++nt) {
        int r = c0 + nt * 32 + ln;
        bf[nt] = ld_frag8(sB + r * 64 + (cc ^ (r & 7)) * 8);
      }
#pragma unroll
      for (int mt = 0; mt < 2; ++mt)
#pragma unroll
        for (int nt = 0; nt < 2; ++nt)
          acc[mt][nt] = __builtin_amdgcn_mfma_f32_32x32x16_bf16(af[mt], bf[nt], acc[mt][nt], 0, 0, 0);
    }
    __syncthreads();
  }

  // epilogue: p = exp(s^2-1) -> LDS (pitch 136, conflict-free) -> coalesced bf16 stores
  unsigned short* sP = smem;
#pragma unroll
  for (int mt = 0; mt < 2; ++mt)
#pragma unroll
    for (int nt = 0; nt < 2; ++nt) {
      const int col = c0 + nt * 32 + ln;
#pragma unroll
      for (int r = 0; r < 16; ++r) {
        float s = acc[mt][nt][r];
        float p = __expf(__builtin_fmaf(s, s, -1.0f));
        int row = r0 + mt * 32 + (r & 3) + 8 * (r >> 2) + 4 * half;
        sP[row * 136 + col] = f32_bf16(p);
      }
    }
  __syncthreads();
  unsigned short* Pg = P + (long)b * SEQ * SEQ;
  float* lwb = lw + b * SEQ + i0;
#pragma unroll
  for (int k = 0; k < 8; ++k) {
    int u = tid + k * 256;
    int row = u >> 4, c16 = u & 15;
    uint4 o = *reinterpret_cast<const uint4*>(sP + row * 136 + c16 * 8);
    *reinterpret_cast<uint4*>(Pg + (long)(i0 + row) * SEQ + j0 + c16 * 8) = o;
    // fused partial row-sum of the exact bf16 P values (16 lanes per row)
    float s = bf_lo(o.x) + bf_hi(o.x) + bf_lo(o.y) + bf_hi(o.y)
            + bf_lo(o.z) + bf_hi(o.z) + bf_lo(o.w) + bf_hi(o.w);
    s += __shfl_xor(s, 1);
    s += __shfl_xor(s, 2);
    s += __shfl_xor(s, 4);
    s += __shfl_xor(s, 8);
    if ((tid & 15) == 0) atomicAdd(&lwb[row], s);
  }
}

// ---------------- gemm2: out[b,i,d] = (P . x) / l ; round-2 proven core ----------------
// grid 512 = 8 batches x 16 i-tiles x 4 d-tiles ; 256 threads = 4 waves
__global__ __launch_bounds__(256, 3) void gemm2_kernel(const unsigned short* __restrict__ P,
                                                       const unsigned short* __restrict__ xt,
                                                       const float* __restrict__ lw,
                                                       float* __restrict__ out) {
  const int b  = blockIdx.x & 7;
  const int t  = blockIdx.x >> 3;
  const int i0 = (t & 15) * 128;
  const int n0 = (t >> 4) * 128;
  const int tid  = threadIdx.x;
  const int w    = tid >> 6;
  const int lane = tid & 63;
  const int ln   = lane & 31;
  const int half = lane >> 5;

  __shared__ __align__(16) unsigned short sA[8192];
  __shared__ __align__(16) unsigned short sB[8192];
  __shared__ float sl[128];

  const unsigned short* Ag = P  + (long)b * SEQ * SEQ + (long)i0 * SEQ;
  const unsigned short* Bg = xt + (long)b * DIM * SEQ + (long)n0 * SEQ;

  if (tid < 128) sl[tid] = lw[b * SEQ + i0 + tid];

  floatx16 acc[2][2];
#pragma unroll
  for (int mt = 0; mt < 2; ++mt)
#pragma unroll
    for (int nt = 0; nt < 2; ++nt)
#pragma unroll
      for (int i = 0; i < 16; ++i) acc[mt][nt][i] = 0.f;

  const int r0 = (w >> 1) * 64;
  const int c0 = (w & 1) * 64;

  for (int kc = 0; kc < 32; ++kc) {
#pragma unroll
    for (int k = 0; k < 4; ++k) {
      int u = tid + k * 256;
      int row = u >> 3, c = u & 7;
      int gc = (c ^ (row & 7)) * 8;
      gld_lds16(Ag + (long)row * SEQ + kc * 64 + gc, sA + u * 8);
      gld_lds16(Bg + (long)row * SEQ + kc * 64 + gc, sB + u * 8);
    }
    __syncthreads();
#pragma unroll
    for (int kk = 0; kk < 4; ++kk) {
      const int cc = kk * 2 + half;
      short8 af[2], bf[2];
#pragma unroll
      for (int mt = 0; mt < 2; ++mt) {
        int r = r0 + mt * 32 + ln;
        af[mt] = ld_frag8(sA + r * 64 + (cc ^ (r & 7)) * 8);
      }
#pragma unroll
      for (int nt = 0; nt < 2; ++nt) {
        int r = c0 + nt * 32 + ln;
        bf[nt] = ld_frag8(sB + r * 64 + (cc ^ (r & 7)) * 8);
      }
#pragma unroll
      for (int mt = 0; mt < 2; ++mt)
#pragma unroll
        for (int nt = 0; nt < 2; ++nt)
          acc[mt][nt] = __builtin_amdgcn_mfma_f32_32x32x16_bf16(af[mt], bf[nt], acc[mt][nt], 0, 0, 0);
    }
    __syncthreads();
  }

  // epilogue: divide by l, coalesced fp32 stores
  float* outb = out + (long)b * SEQ * DIM;
#pragma unroll
  for (int mt = 0; mt < 2; ++mt)
#pragma unroll
    for (int r = 0; r < 16; ++r) {
      const int row = r0 + mt * 32 + (r & 3) + 8 * (r >> 2) + 4 * half;
      const float inv = 1.0f / sl[row];
#pragma unroll
      for (int nt = 0; nt < 2; ++nt) {
        const int col = c0 + nt * 32 + ln;
        outb[(long)(i0 + row) * DIM + n0 + col] = acc[mt][nt][r] * inv;
      }
    }
}

extern "C" void kernel_launch(void* const* d_in, const int* in_sizes, int n_in,
                              void* d_out, int out_size, void* d_ws, size_t ws_size,
                              hipStream_t stream) {
  const float* x = (const float*)d_in[0];
  float* outp = (float*)d_out;

  unsigned short* xn = (unsigned short*)d_ws;                        // 16.78 MB
  unsigned short* xt = xn + (size_t)BATCH * SEQ * DIM;               // 16.78 MB
  unsigned short* Pw = xt + (size_t)BATCH * SEQ * DIM;               // 67.1 MB
  float*          lw = (float*)(Pw + (size_t)BATCH * SEQ * SEQ);     // 64 KB

  hipMemsetAsync(lw, 0, (size_t)BATCH * SEQ * sizeof(float), stream);
  prep_kernel <<<BATCH * (SEQ / 64), 512, 0, stream>>>(x, xn, xt);
  gemm1_kernel<<<BATCH * 16 * 16,    256, 0, stream>>>(xn, Pw, lw);
  gemm2_kernel<<<BATCH * 16 * 4,     256, 0, stream>>>(Pw, xt, lw, outp);
}

// Round 7
// 166.801 us; speedup vs baseline: 1.0909x; 1.0122x over previous
//
#include <hip/hip_runtime.h>
#include <stdint.h>

#define BATCH 8
#define SEQ   2048
#define DIM   512

typedef __attribute__((ext_vector_type(8)))  short short8;    // 8 bf16 (4 VGPRs)
typedef __attribute__((ext_vector_type(16))) float floatx16;  // 32x32 C/D frag

static __device__ __forceinline__ unsigned short f32_bf16(float f) {
  unsigned u = __builtin_bit_cast(unsigned, f);
  u += 0x7FFFu + ((u >> 16) & 1u);          // round-to-nearest-even
  return (unsigned short)(u >> 16);
}
static __device__ __forceinline__ short8 ld_frag8(const unsigned short* p) {
  return __builtin_bit_cast(short8, *reinterpret_cast<const uint4*>(p));
}
static __device__ __forceinline__ void gld_lds16(const unsigned short* g, unsigned short* l) {
  __builtin_amdgcn_global_load_lds((const __attribute__((address_space(1))) unsigned int*)g,
                                   (__attribute__((address_space(3))) unsigned int*)l, 16, 0, 0);
}
static __device__ __forceinline__ float bf_lo(unsigned u) {
  return __builtin_bit_cast(float, u << 16);
}
static __device__ __forceinline__ float bf_hi(unsigned u) {
  return __builtin_bit_cast(float, u & 0xFFFF0000u);
}

// ---------------- prep: x -> xn (bf16 x-hat, row-major) and xt (bf16 x^T, [b][d][j]) --------
// grid 512 = 8 batches (XCD-pinned &7) x 64 j-tiles of 32 rows ; 256 threads -> ~4 blocks/CU
__global__ __launch_bounds__(256) void prep_kernel(const float* __restrict__ x,
                                                   unsigned short* __restrict__ xn,
                                                   unsigned short* __restrict__ xt) {
  const int b   = blockIdx.x & 7;
  const int jt  = blockIdx.x >> 3;     // 0..63
  const int t   = threadIdx.x;
  const int row = t >> 3;              // 0..31
  const int oct = t & 7;               // 0..7

  __shared__ unsigned short xs[512 * 34];   // [d][j] bf16, pitch 34 u16 (34.8 KB)

  const long rowg = ((long)b * SEQ + jt * 32 + row) * DIM;
  const float* xp = x + rowg;

  float4 v[16];
#pragma unroll
  for (int k = 0; k < 16; ++k)
    v[k] = *reinterpret_cast<const float4*>(xp + k * 32 + oct * 4);

  float acc = 0.f;
#pragma unroll
  for (int k = 0; k < 16; ++k)
    acc += v[k].x*v[k].x + v[k].y*v[k].y + v[k].z*v[k].z + v[k].w*v[k].w;
  acc += __shfl_xor(acc, 1);
  acc += __shfl_xor(acc, 2);
  acc += __shfl_xor(acc, 4);
  const float sc = 1.f / (sqrtf(acc) + 1e-12f);

  // xn straight from registers
  unsigned short* xnp = xn + rowg + oct * 4;
#pragma unroll
  for (int k = 0; k < 16; ++k) {
    ushort4 pk;
    pk.x = f32_bf16(v[k].x * sc); pk.y = f32_bf16(v[k].y * sc);
    pk.z = f32_bf16(v[k].z * sc); pk.w = f32_bf16(v[k].w * sc);
    *reinterpret_cast<ushort4*>(xnp + k * 32) = pk;
  }

  // LDS transpose staging: scalar u16 writes, bank = 4*oct + row/2 + const -> free
#pragma unroll
  for (int k = 0; k < 16; ++k) {
    const int d = k * 32 + oct * 4;
    xs[(d + 0) * 34 + row] = f32_bf16(v[k].x);
    xs[(d + 1) * 34 + row] = f32_bf16(v[k].y);
    xs[(d + 2) * 34 + row] = f32_bf16(v[k].z);
    xs[(d + 3) * 34 + row] = f32_bf16(v[k].w);
  }
  __syncthreads();

  // xt: 64B segments per d-row; jt-adjacent blocks (same XCD) complete 128B lines in L2
  unsigned short* xtb = xt + (long)b * DIM * SEQ + jt * 32;
  const int wv = t >> 6, li = t & 63, dsub = li >> 2, jc = li & 3;
#pragma unroll
  for (int it = 0; it < 8; ++it) {
    const int d = it * 64 + wv * 16 + dsub;
    const unsigned* bp = reinterpret_cast<const unsigned*>(&xs[d * 34]);
    uint4 o;
    o.x = bp[jc * 4 + 0]; o.y = bp[jc * 4 + 1];
    o.z = bp[jc * 4 + 2]; o.w = bp[jc * 4 + 3];
    *reinterpret_cast<uint4*>(xtb + (long)d * SEQ + jc * 8) = o;
  }
}

// ---------------- gemm1: P[b,i,j] = bf16(exp(S^2-1)), S = xn.xn^T ; fused cheap partials --
// grid 2048 = 8 batches x 16 i x 16 j ; 256 threads = 4 waves ; 4 blocks/CU
__global__ __launch_bounds__(256, 4) void gemm1_kernel(const unsigned short* __restrict__ xn,
                                                       unsigned short* __restrict__ P,
                                                       float* __restrict__ lw) {
  const int b  = blockIdx.x & 7;
  const int t  = blockIdx.x >> 3;
  const int i0 = (t & 15) * 128;
  const int j0 = (t >> 4) * 128;
  const int tid  = threadIdx.x;
  const int w    = tid >> 6;
  const int lane = tid & 63;
  const int ln   = lane & 31;
  const int half = lane >> 5;

  __shared__ __align__(16) unsigned short smem[17408];   // staging 32KB ; epilogue sP 128x136
  unsigned short* sA = smem;
  unsigned short* sB = smem + 8192;

  const unsigned short* xb = xn + (long)b * SEQ * DIM;
  const unsigned short* Ag = xb + (long)i0 * DIM;
  const unsigned short* Bg = xb + (long)j0 * DIM;

  floatx16 acc[2][2];
#pragma unroll
  for (int mt = 0; mt < 2; ++mt)
#pragma unroll
    for (int nt = 0; nt < 2; ++nt)
#pragma unroll
      for (int i = 0; i < 16; ++i) acc[mt][nt][i] = 0.f;

  const int r0 = (w >> 1) * 64;
  const int c0 = (w & 1) * 64;

  for (int kc = 0; kc < 8; ++kc) {
#pragma unroll
    for (int k = 0; k < 4; ++k) {
      int u = tid + k * 256;
      int row = u >> 3, c = u & 7;
      int gc = (c ^ ((row ^ (row >> 3)) & 7)) * 8;   // conflict-free swizzle key
      gld_lds16(Ag + (long)row * DIM + kc * 64 + gc, sA + u * 8);
      gld_lds16(Bg + (long)row * DIM + kc * 64 + gc, sB + u * 8);
    }
    __syncthreads();
#pragma unroll
    for (int kk = 0; kk < 4; ++kk) {
      const int cc = kk * 2 + half;
      short8 af[2], bf[2];
#pragma unroll
      for (int mt = 0; mt < 2; ++mt) {
        int r = r0 + mt * 32 + ln;
        af[mt] = ld_frag8(sA + r * 64 + ((cc ^ ((r ^ (r >> 3)) & 7)) * 8));
      }
#pragma unroll
      for (int nt = 0; nt < 2; ++nt) {
        int r = c0 + nt * 32 + ln;
        bf[nt] = ld_frag8(sB + r * 64 + ((cc ^ ((r ^ (r >> 3)) & 7)) * 8));
      }
#pragma unroll
      for (int mt = 0; mt < 2; ++mt)
#pragma unroll
        for (int nt = 0; nt < 2; ++nt)
          acc[mt][nt] = __builtin_amdgcn_mfma_f32_32x32x16_bf16(af[mt], bf[nt], acc[mt][nt], 0, 0, 0);
    }
    __syncthreads();
  }

  // epilogue: p = exp(s^2-1) -> LDS (pitch 136, conflict-free) -> coalesced bf16 stores
  unsigned short* sP = smem;
#pragma unroll
  for (int mt = 0; mt < 2; ++mt)
#pragma unroll
    for (int nt = 0; nt < 2; ++nt) {
      const int col = c0 + nt * 32 + ln;
#pragma unroll
      for (int r = 0; r < 16; ++r) {
        float s = acc[mt][nt][r];
        float p = __expf(__builtin_fmaf(s, s, -1.0f));
        int row = r0 + mt * 32 + (r & 3) + 8 * (r >> 2) + 4 * half;
        sP[row * 136 + col] = f32_bf16(p);
      }
    }
  __syncthreads();
  unsigned short* Pg = P + (long)b * SEQ * SEQ;
  float* lwb = lw + b * SEQ + i0;
#pragma unroll
  for (int k = 0; k < 8; ++k) {
    int u = tid + k * 256;
    int row = u >> 4, c16 = u & 15;
    uint4 o = *reinterpret_cast<const uint4*>(sP + row * 136 + c16 * 8);
    *reinterpret_cast<uint4*>(Pg + (long)(i0 + row) * SEQ + j0 + c16 * 8) = o;
    // fused partial row-sum of the exact bf16 P values (16 lanes per row)
    float s = bf_lo(o.x) + bf_hi(o.x) + bf_lo(o.y) + bf_hi(o.y)
            + bf_lo(o.z) + bf_hi(o.z) + bf_lo(o.w) + bf_hi(o.w);
    s += __shfl_xor(s, 1);
    s += __shfl_xor(s, 2);
    s += __shfl_xor(s, 4);
    s += __shfl_xor(s, 8);
    if ((tid & 15) == 0) atomicAdd(&lwb[row], s);
  }
}

// ---------------- gemm2: out[b,i,d] = (P . x) / l ----------------
// grid 512 = 8 batches x 16 i-tiles x 4 d-tiles ; 256 threads = 4 waves
__global__ __launch_bounds__(256, 3) void gemm2_kernel(const unsigned short* __restrict__ P,
                                                       const unsigned short* __restrict__ xt,
                                                       const float* __restrict__ lw,
                                                       float* __restrict__ out) {
  const int b  = blockIdx.x & 7;
  const int t  = blockIdx.x >> 3;
  const int i0 = (t & 15) * 128;
  const int n0 = (t >> 4) * 128;
  const int tid  = threadIdx.x;
  const int w    = tid >> 6;
  const int lane = tid & 63;
  const int ln   = lane & 31;
  const int half = lane >> 5;

  __shared__ __align__(16) unsigned short sA[8192];
  __shared__ __align__(16) unsigned short sB[8192];
  __shared__ float sl[128];

  const unsigned short* Ag = P  + (long)b * SEQ * SEQ + (long)i0 * SEQ;
  const unsigned short* Bg = xt + (long)b * DIM * SEQ + (long)n0 * SEQ;

  if (tid < 128) sl[tid] = lw[b * SEQ + i0 + tid];

  floatx16 acc[2][2];
#pragma unroll
  for (int mt = 0; mt < 2; ++mt)
#pragma unroll
    for (int nt = 0; nt < 2; ++nt)
#pragma unroll
      for (int i = 0; i < 16; ++i) acc[mt][nt][i] = 0.f;

  const int r0 = (w >> 1) * 64;
  const int c0 = (w & 1) * 64;

  for (int kc = 0; kc < 32; ++kc) {
#pragma unroll
    for (int k = 0; k < 4; ++k) {
      int u = tid + k * 256;
      int row = u >> 3, c = u & 7;
      int gc = (c ^ ((row ^ (row >> 3)) & 7)) * 8;   // conflict-free swizzle key
      gld_lds16(Ag + (long)row * SEQ + kc * 64 + gc, sA + u * 8);
      gld_lds16(Bg + (long)row * SEQ + kc * 64 + gc, sB + u * 8);
    }
    __syncthreads();
#pragma unroll
    for (int kk = 0; kk < 4; ++kk) {
      const int cc = kk * 2 + half;
      short8 af[2], bf[2];
#pragma unroll
      for (int mt = 0; mt < 2; ++mt) {
        int r = r0 + mt * 32 + ln;
        af[mt] = ld_frag8(sA + r * 64 + ((cc ^ ((r ^ (r >> 3)) & 7)) * 8));
      }
#pragma unroll
      for (int nt = 0; nt < 2; ++nt) {
        int r = c0 + nt * 32 + ln;
        bf[nt] = ld_frag8(sB + r * 64 + ((cc ^ ((r ^ (r >> 3)) & 7)) * 8));
      }
#pragma unroll
      for (int mt = 0; mt < 2; ++mt)
#pragma unroll
        for (int nt = 0; nt < 2; ++nt)
          acc[mt][nt] = __builtin_amdgcn_mfma_f32_32x32x16_bf16(af[mt], bf[nt], acc[mt][nt], 0, 0, 0);
    }
    __syncthreads();
  }

  // epilogue: divide by l, coalesced fp32 stores
  float* outb = out + (long)b * SEQ * DIM;
#pragma unroll
  for (int mt = 0; mt < 2; ++mt)
#pragma unroll
    for (int r = 0; r < 16; ++r) {
      const int row = r0 + mt * 32 + (r & 3) + 8 * (r >> 2) + 4 * half;
      const float inv = 1.0f / sl[row];
#pragma unroll
      for (int nt = 0; nt < 2; ++nt) {
        const int col = c0 + nt * 32 + ln;
        outb[(long)(i0 + row) * DIM + n0 + col] = acc[mt][nt][r] * inv;
      }
    }
}

extern "C" void kernel_launch(void* const* d_in, const int* in_sizes, int n_in,
                              void* d_out, int out_size, void* d_ws, size_t ws_size,
                              hipStream_t stream) {
  const float* x = (const float*)d_in[0];
  float* outp = (float*)d_out;

  unsigned short* xn = (unsigned short*)d_ws;                        // 16.78 MB
  unsigned short* xt = xn + (size_t)BATCH * SEQ * DIM;               // 16.78 MB
  unsigned short* Pw = xt + (size_t)BATCH * SEQ * DIM;               // 67.1 MB
  float*          lw = (float*)(Pw + (size_t)BATCH * SEQ * SEQ);     // 64 KB

  hipMemsetAsync(lw, 0, (size_t)BATCH * SEQ * sizeof(float), stream);
  prep_kernel <<<BATCH * (SEQ / 32), 256, 0, stream>>>(x, xn, xt);
  gemm1_kernel<<<BATCH * 16 * 16,    256, 0, stream>>>(xn, Pw, lw);
  gemm2_kernel<<<BATCH * 16 * 4,     256, 0, stream>>>(Pw, xt, lw, outp);
}